// Round 2
// baseline (40.745 us; speedup 1.0000x reference)
//
#include <hip/hip_runtime.h>
#include <math.h>

// BettingLoss: scalar loss over B=1048576 races, T=8 dogs.
// Inputs (float32, each B*T): predicted_probs, true_winners(one-hot),
// market_odds, gumbel_noise. Output: 1 float32 scalar.
//
// R1: latency-bound fix — 2 races/thread with all 16 float4 loads issued
// up front (MLP), __launch_bounds__(256,4) for a 128-VGPR budget,
// v_rcp_f32 instead of full-precision divides, grid fills all wave slots.

constexpr int T = 8;
constexpr int NB = 2048;  // blocks in main kernel (2048*256 threads * 2 races)
constexpr int NT = 256;   // threads per block
constexpr int RPT = 2;    // races per thread

__device__ __forceinline__ float fastrcp(float x) {
  return __builtin_amdgcn_rcpf(x);
}

// accumulator indices: 0=cnt, 1=sum(ce*valid), 2=sum(ce), 3=sum(soft_ep*valid),
// 4=sum(max_prob), 5=sum(entropy)
__global__ __launch_bounds__(NT, 4) void betting_main(
    const float* __restrict__ pp, const float* __restrict__ tw,
    const float* __restrict__ mo, const float* __restrict__ gn,
    float* __restrict__ partials, int nraces) {
  const int tid = blockIdx.x * NT + threadIdx.x;
  const int ntot = gridDim.x * NT;

  const float4* __restrict__ pp4 = (const float4*)pp;
  const float4* __restrict__ tw4 = (const float4*)tw;
  const float4* __restrict__ mo4 = (const float4*)mo;
  const float4* __restrict__ gn4 = (const float4*)gn;

  // ---- issue ALL loads first (16x float4 in flight) ----
  float4 A[RPT][2], W[RPT][2], O[RPT][2], G[RPT][2];
  float wgt[RPT];
#pragma unroll
  for (int k = 0; k < RPT; ++k) {
    int r = tid + k * ntot;
    wgt[k] = (r < nraces) ? 1.f : 0.f;
    r = min(r, nraces - 1);
    A[k][0] = pp4[2 * r]; A[k][1] = pp4[2 * r + 1];
    W[k][0] = tw4[2 * r]; W[k][1] = tw4[2 * r + 1];
    O[k][0] = mo4[2 * r]; O[k][1] = mo4[2 * r + 1];
    G[k][0] = gn4[2 * r]; G[k][1] = gn4[2 * r + 1];
  }

  float acc[6] = {0.f, 0.f, 0.f, 0.f, 0.f, 0.f};

#pragma unroll
  for (int k = 0; k < RPT; ++k) {
    float p[T] = {A[k][0].x, A[k][0].y, A[k][0].z, A[k][0].w,
                  A[k][1].x, A[k][1].y, A[k][1].z, A[k][1].w};
    float w[T] = {W[k][0].x, W[k][0].y, W[k][0].z, W[k][0].w,
                  W[k][1].x, W[k][1].y, W[k][1].z, W[k][1].w};
    float o[T] = {O[k][0].x, O[k][0].y, O[k][0].z, O[k][0].w,
                  O[k][1].x, O[k][1].y, O[k][1].z, O[k][1].w};
    float g[T] = {G[k][0].x, G[k][0].y, G[k][0].z, G[k][0].w,
                  G[k][1].x, G[k][1].y, G[k][1].z, G[k][1].w};

    // ---- validity ----
    bool anypos = false;
    float simp = 0.f;
#pragma unroll
    for (int t = 0; t < T; ++t) {
      anypos = anypos || (o[t] > 0.f);
      simp += fastrcp(fmaxf(o[t], 1.01f));
    }
    bool valid = anypos && (simp >= 0.95f);
    float vf = valid ? 1.f : 0.f;

    // ---- expected profit per dog (masked) ----
    float ep[T];
#pragma unroll
    for (int t = 0; t < T; ++t)
      ep[t] = valid ? (o[t] * 1.1f * p[t] - 1.f) * (0.02f * 0.95f) : 0.f;

    // ---- gumbel-softmax selection: softmax(ep*100 + g*10) ----
    float z[T], zm = -INFINITY;
#pragma unroll
    for (int t = 0; t < T; ++t) {
      z[t] = ep[t] * 100.f + g[t] * 10.f;
      zm = fmaxf(zm, z[t]);
    }
    float s2 = 0.f, sp = 0.f;
#pragma unroll
    for (int t = 0; t < T; ++t) {
      float e = __expf(z[t] - zm);
      s2 += e;
      sp += e * ep[t];
    }
    float soft_ep = sp * fastrcp(s2);

    // ---- cross-entropy: probs treated as logits ----
    float m = -INFINITY;
#pragma unroll
    for (int t = 0; t < T; ++t) m = fmaxf(m, p[t]);
    float se = 0.f, plabel = 0.f;
#pragma unroll
    for (int t = 0; t < T; ++t) {
      se += __expf(p[t] - m);
      plabel += w[t] * p[t];  // one-hot exact
    }
    float ce = m + __logf(se) - plabel;

    // ---- entropy of predicted_probs ----
    float ent = 0.f;
#pragma unroll
    for (int t = 0; t < T; ++t) ent -= p[t] * __logf(p[t] + 1e-8f);

    const float wg = wgt[k];
    acc[0] += vf * wg;
    acc[1] += ce * vf * wg;
    acc[2] += ce * wg;
    acc[3] += soft_ep * vf * wg;
    acc[4] += m * wg;  // max prob (same max as log-softmax max)
    acc[5] += ent * wg;
  }

  // ---- block reduction: wave shfl -> LDS -> partials ----
  __shared__ float red[NT / 64][6];
#pragma unroll
  for (int k = 0; k < 6; ++k) {
#pragma unroll
    for (int off = 32; off >= 1; off >>= 1) acc[k] += __shfl_down(acc[k], off);
  }
  int lane = threadIdx.x & 63, wave = threadIdx.x >> 6;
  if (lane == 0) {
#pragma unroll
    for (int k = 0; k < 6; ++k) red[wave][k] = acc[k];
  }
  __syncthreads();
  if (threadIdx.x == 0) {
#pragma unroll
    for (int k = 0; k < 6; ++k) {
      float s = 0.f;
      for (int wv = 0; wv < NT / 64; ++wv) s += red[wv][k];
      partials[k * gridDim.x + blockIdx.x] = s;  // SoA for coalesced finalize
    }
  }
}

__global__ __launch_bounds__(NT) void betting_final(
    const float* __restrict__ partials, int nb, float* __restrict__ out,
    double Bd) {
  __shared__ double red[NT / 64][6];
  double a[6] = {0, 0, 0, 0, 0, 0};
#pragma unroll
  for (int k = 0; k < 6; ++k)
    for (int i = threadIdx.x; i < nb; i += NT) a[k] += (double)partials[k * nb + i];
#pragma unroll
  for (int k = 0; k < 6; ++k) {
#pragma unroll
    for (int off = 32; off >= 1; off >>= 1) a[k] += __shfl_down(a[k], off);
  }
  int lane = threadIdx.x & 63, wave = threadIdx.x >> 6;
  if (lane == 0) {
#pragma unroll
    for (int k = 0; k < 6; ++k) red[wave][k] = a[k];
  }
  __syncthreads();
  if (threadIdx.x == 0) {
    double s[6];
#pragma unroll
    for (int k = 0; k < 6; ++k) {
      s[k] = 0.0;
      for (int wv = 0; wv < NT / 64; ++wv) s[k] += red[wv][k];
    }
    double cnt = s[0], Scev = s[1], Sce = s[2], Ssoft = s[3], Smax = s[4],
           Sent = s[5];
    double pred = (cnt > 0.0) ? Scev / fmax(cnt, 1.0) : Sce / Bd;
    double conf = -(Smax / Bd) * 0.1;
    double bet = (cnt > 0.0) ? -Ssoft / Bd : conf;
    double ent = Sent / Bd;
    double lam = fmin(0.5 + cnt / 10000.0 * 0.5, 1.0);
    out[0] = (float)(pred + lam * bet - 0.01 * ent);
  }
}

extern "C" void kernel_launch(void* const* d_in, const int* in_sizes, int n_in,
                              void* d_out, int out_size, void* d_ws,
                              size_t ws_size, hipStream_t stream) {
  const float* pp = (const float*)d_in[0];
  const float* tw = (const float*)d_in[1];
  const float* mo = (const float*)d_in[2];
  const float* gn = (const float*)d_in[3];
  float* out = (float*)d_out;
  float* partials = (float*)d_ws;  // 6 * NB floats = 48 KB

  int nraces = in_sizes[0] / T;

  betting_main<<<NB, NT, 0, stream>>>(pp, tw, mo, gn, partials, nraces);
  betting_final<<<1, NT, 0, stream>>>(partials, NB, out, (double)nraces);
}